// Round 1
// baseline (126.774 us; speedup 1.0000x reference)
//
#include <hip/hip_runtime.h>
#include <hip/hip_bf16.h>

typedef __attribute__((ext_vector_type(8))) short  short8;
typedef __attribute__((ext_vector_type(4))) float  floatx4;

#define MFMA16(a, b, c) __builtin_amdgcn_mfma_f32_16x16x32_bf16((a), (b), (c), 0, 0, 0)

// round-to-nearest-even f32 -> bf16 (inputs are finite; NaN not handled)
__device__ __forceinline__ short f2bf(float f) {
    unsigned u = __builtin_bit_cast(unsigned, f);
    u += 0x7fffu + ((u >> 16) & 1u);
    return (short)(u >> 16);
}

constexpr int kB       = 32768;
constexpr int kC       = 4;
constexpr int kD       = 64;
constexpr int kT       = 16;
constexpr int kO       = 32;
constexpr int kNCol    = kT * kO;     // 512
constexpr int kRows    = 16;          // rows per m-tile (one MFMA M)
constexpr int kGrid    = 1024;
constexpr int kTiles   = (kB / kRows) / kGrid;  // 2 persistent tiles per WG

__global__ __launch_bounds__(256) void tok_kernel(
    const float* __restrict__ x,    // [B][C][D]
    const float* __restrict__ Wg,   // [T][O][D]
    const float* __restrict__ bg,   // [T][O]
    const float* __restrict__ Wm,   // [T][C]
    float* __restrict__ out)        // [B][T*O]
{
    const int tid  = threadIdx.x;
    const int lane = tid & 63;
    const int wv   = tid >> 6;      // wave 0..3 -> token group
    const int l15  = lane & 15;
    const int lg   = lane >> 4;     // 0..3 (k-slot group / row group)
    const int t0   = wv * 4;

    // ---- per-wave constant setup: B fragments from W_gen, merge weights, fused bias ----
    // B-frag (16x16x32, K=d): lane holds col o = nf*16 + (l&15), k = ks*32 + lg*8 + j
    short8 bfrag[4][2][2];
    float  wmv[4][4];
    float  biasv[4][2];
#pragma unroll
    for (int tt = 0; tt < 4; ++tt) {
        const int t = t0 + tt;
        float S = 0.f;
#pragma unroll
        for (int c = 0; c < kC; ++c) { wmv[tt][c] = Wm[t*kC + c]; S += wmv[tt][c]; }
#pragma unroll
        for (int nf = 0; nf < 2; ++nf) {
            biasv[tt][nf] = bg[t*kO + nf*16 + l15] * S;
#pragma unroll
            for (int ks = 0; ks < 2; ++ks) {
                const float* src = Wg + (size_t)(t*kO + nf*16 + l15)*kD + ks*32 + lg*8;
                floatx4 a = *reinterpret_cast<const floatx4*>(src);
                floatx4 b = *reinterpret_cast<const floatx4*>(src + 4);
                short8 f;
                f[0]=f2bf(a[0]); f[1]=f2bf(a[1]); f[2]=f2bf(a[2]); f[3]=f2bf(a[3]);
                f[4]=f2bf(b[0]); f[5]=f2bf(b[1]); f[6]=f2bf(b[2]); f[7]=f2bf(b[3]);
                bfrag[tt][nf][ks] = f;
            }
        }
    }

#pragma unroll 1   // keep the two persistent tiles serial (register pressure)
    for (int it = 0; it < kTiles; ++it) {
        const int tile = blockIdx.x + it*kGrid;
        const int brow = tile*kRows + l15;
        const float* xr = x + (size_t)brow * (kC*kD);

        // x in A-fragment lane layout: xv[ks][c][j] = x[brow][c][ks*32 + lg*8 + j]
        float xv[2][kC][8];
#pragma unroll
        for (int ks = 0; ks < 2; ++ks)
#pragma unroll
        for (int c = 0; c < kC; ++c) {
            const float* p = xr + c*kD + ks*32 + lg*8;
            floatx4 lo = *reinterpret_cast<const floatx4*>(p);
            floatx4 hi = *reinterpret_cast<const floatx4*>(p + 4);
            xv[ks][c][0]=lo[0]; xv[ks][c][1]=lo[1]; xv[ks][c][2]=lo[2]; xv[ks][c][3]=lo[3];
            xv[ks][c][4]=hi[0]; xv[ks][c][5]=hi[1]; xv[ks][c][6]=hi[2]; xv[ks][c][7]=hi[3];
        }

        floatx4 acc0[4] = {{0.f,0.f,0.f,0.f},{0.f,0.f,0.f,0.f},{0.f,0.f,0.f,0.f},{0.f,0.f,0.f,0.f}};
        floatx4 acc1[4] = {{0.f,0.f,0.f,0.f},{0.f,0.f,0.f,0.f},{0.f,0.f,0.f,0.f},{0.f,0.f,0.f,0.f}};

#pragma unroll
        for (int tt = 0; tt < 4; ++tt) {
#pragma unroll
            for (int ks = 0; ks < 2; ++ks) {
                // channel-merge in f32, then pack A fragment (bf16)
                short8 af;
#pragma unroll
                for (int j = 0; j < 8; ++j) {
                    float v = xv[ks][0][j] * wmv[tt][0];
                    v = fmaf(xv[ks][1][j], wmv[tt][1], v);
                    v = fmaf(xv[ks][2][j], wmv[tt][2], v);
                    v = fmaf(xv[ks][3][j], wmv[tt][3], v);
                    af[j] = f2bf(v);
                }
                acc0[tt] = MFMA16(af, bfrag[tt][0][ks], acc0[tt]);
                acc1[tt] = MFMA16(af, bfrag[tt][1][ks], acc1[tt]);
            }
        }

        // epilogue: bias + relu + store. D-frag: col = l&15 (o), row = lg*4 + r (b)
        const int bbase = tile*kRows + lg*4;
#pragma unroll
        for (int tt = 0; tt < 4; ++tt) {
            const int t = t0 + tt;
#pragma unroll
            for (int nf = 0; nf < 2; ++nf) {
                const int col = t*kO + nf*16 + l15;
                const float bia = biasv[tt][nf];
#pragma unroll
                for (int r = 0; r < 4; ++r) {
                    float v = (nf == 0 ? acc0[tt][r] : acc1[tt][r]) + bia;
                    v = v > 0.f ? v : 0.f;
                    out[(size_t)(bbase + r)*kNCol + col] = v;
                }
            }
        }
    }
}

extern "C" void kernel_launch(void* const* d_in, const int* in_sizes, int n_in,
                              void* d_out, int out_size, void* d_ws, size_t ws_size,
                              hipStream_t stream)
{
    const float* x  = (const float*)d_in[0];
    const float* Wg = (const float*)d_in[1];
    const float* bg = (const float*)d_in[2];
    const float* Wm = (const float*)d_in[3];
    float* out = (float*)d_out;
    tok_kernel<<<kGrid, 256, 0, stream>>>(x, Wg, bg, Wm, out);
}

// Round 9
// 120.085 us; speedup vs baseline: 1.0557x; 1.0557x over previous
//
#include <hip/hip_runtime.h>
#include <hip/hip_bf16.h>

typedef __attribute__((ext_vector_type(8))) short  short8;
typedef __attribute__((ext_vector_type(4))) float  floatx4;

#define MFMA16(a, b, c) __builtin_amdgcn_mfma_f32_16x16x32_bf16((a), (b), (c), 0, 0, 0)

// round-to-nearest-even f32 -> bf16 (inputs finite)
__device__ __forceinline__ short f2bf(float f) {
    unsigned u = __builtin_bit_cast(unsigned, f);
    u += 0x7fffu + ((u >> 16) & 1u);
    return (short)(u >> 16);
}

constexpr int kC     = 4;
constexpr int kD     = 64;
constexpr int kT     = 16;
constexpr int kO     = 32;
constexpr int kNCol  = kT * kO;   // 512
constexpr int kPad   = 260;       // 256 floats + 4 pad -> row stride 1040 B
constexpr int kGrid  = 2048;      // one 16-row tile per WG
constexpr int kThr   = 256;       // 4 waves; wave w owns tokens 4w..4w+3 (round-1 config)

__global__ __launch_bounds__(kThr) void tok_kernel(
    const float* __restrict__ x,    // [B][C][D]  (row = 1024 B)
    const float* __restrict__ Wg,   // [T][O][D]
    const float* __restrict__ bg,   // [T][O]
    const float* __restrict__ Wm,   // [T][C]
    float* __restrict__ out)        // [B][T*O]
{
    // ROUND-8 BISECT: round-7's minimal LDS staging (linear + pad, plain
    // __syncthreads) but with round-1's PROVEN exec config: 256 thr / 4 waves /
    // 4 tokens per wave / no launch-bounds VGPR cap / single tile per WG.
    // One 16-row tile, one barrier, no double-buffer.
    __shared__ alignas(16) float lds[16][kPad];

    const int tid  = threadIdx.x;
    const int lane = tid & 63;
    const int wv   = tid >> 6;          // 0..3
    const int l15  = lane & 15;
    const int lg   = lane >> 4;         // 0..3
    const int t0   = wv * 4;

    const int tile = blockIdx.x;

    // ---- reg-stage: coalesced loads, wave wv covers rows {i*4+wv}, lane l bytes [16l,16l+16) ----
    floatx4 stg[4];
#pragma unroll
    for (int i = 0; i < 4; ++i) {
        const int grow = tile * 16 + i * 4 + wv;
        stg[i] = *reinterpret_cast<const floatx4*>(
            (const char*)x + (size_t)grow * 1024 + (unsigned)lane * 16);
    }

    // ---- per-wave constants while staged loads fly (identical to round-1 pass) ----
    float  wmv[4][4];
    short8 bfrag[4][2][2];   // [tt][nf][ks]
    float  biasv[4][2];
#pragma unroll
    for (int tt = 0; tt < 4; ++tt) {
        const int t = t0 + tt;
        float s = 0.f;
#pragma unroll
        for (int c = 0; c < kC; ++c) { wmv[tt][c] = Wm[t * kC + c]; s += wmv[tt][c]; }
#pragma unroll
        for (int nf = 0; nf < 2; ++nf) {
            biasv[tt][nf] = bg[t * kO + nf * 16 + l15] * s;
#pragma unroll
            for (int ks = 0; ks < 2; ++ks) {
                const float* src = Wg + (size_t)(t * kO + nf * 16 + l15) * kD + ks * 32 + lg * 8;
                floatx4 a = *reinterpret_cast<const floatx4*>(src);
                floatx4 b = *reinterpret_cast<const floatx4*>(src + 4);
                short8 f;
                f[0] = f2bf(a[0]); f[1] = f2bf(a[1]); f[2] = f2bf(a[2]); f[3] = f2bf(a[3]);
                f[4] = f2bf(b[0]); f[5] = f2bf(b[1]); f[6] = f2bf(b[2]); f[7] = f2bf(b[3]);
                bfrag[tt][nf][ks] = f;
            }
        }
    }

    // ---- linear ds_write of the tile, one barrier ----
#pragma unroll
    for (int i = 0; i < 4; ++i) {
        const int row = i * 4 + wv;
        *reinterpret_cast<floatx4*>(
            (char*)&lds[row][0] + (unsigned)lane * 16) = stg[i];
    }
    __syncthreads();

    // ---- compute (byte-identical math to round-1 pass, source = LDS row l15) ----
    floatx4 acc[4][2] = {};
    const char* rowp = (const char*)&lds[l15][0];
#pragma unroll
    for (int ks = 0; ks < 2; ++ks) {
        floatx4 xlo[4], xhi[4];
#pragma unroll
        for (int c = 0; c < 4; ++c) {
            const unsigned q = (unsigned)(c * 256 + ks * 128 + lg * 32);
            xlo[c] = *reinterpret_cast<const floatx4*>(rowp + q);
            xhi[c] = *reinterpret_cast<const floatx4*>(rowp + q + 16u);
        }
#pragma unroll
        for (int tt = 0; tt < 4; ++tt) {
            short8 af;
#pragma unroll
            for (int j = 0; j < 4; ++j) {
                float v = xlo[0][j] * wmv[tt][0];
                v = fmaf(xlo[1][j], wmv[tt][1], v);
                v = fmaf(xlo[2][j], wmv[tt][2], v);
                v = fmaf(xlo[3][j], wmv[tt][3], v);
                af[j] = f2bf(v);
            }
#pragma unroll
            for (int j = 0; j < 4; ++j) {
                float v = xhi[0][j] * wmv[tt][0];
                v = fmaf(xhi[1][j], wmv[tt][1], v);
                v = fmaf(xhi[2][j], wmv[tt][2], v);
                v = fmaf(xhi[3][j], wmv[tt][3], v);
                af[4 + j] = f2bf(v);
            }
            acc[tt][0] = MFMA16(af, bfrag[tt][0][ks], acc[tt][0]);
            acc[tt][1] = MFMA16(af, bfrag[tt][1][ks], acc[tt][1]);
        }
    }

    // ---- epilogue: bias + relu + store (round-1 pattern). col = o, row = lg*4 + r ----
    const int rowbase = tile * 16 + lg * 4;
#pragma unroll
    for (int tt = 0; tt < 4; ++tt) {
#pragma unroll
        for (int nf = 0; nf < 2; ++nf) {
            const int col = (t0 + tt) * kO + nf * 16 + l15;
            const float bia = biasv[tt][nf];
#pragma unroll
            for (int r = 0; r < 4; ++r) {
                float v = acc[tt][nf][r] + bia;
                out[(size_t)(rowbase + r) * kNCol + col] = v > 0.f ? v : 0.f;
            }
        }
    }
}

extern "C" void kernel_launch(void* const* d_in, const int* in_sizes, int n_in,
                              void* d_out, int out_size, void* d_ws, size_t ws_size,
                              hipStream_t stream)
{
    const float* x  = (const float*)d_in[0];
    const float* Wg = (const float*)d_in[1];
    const float* bg = (const float*)d_in[2];
    const float* Wm = (const float*)d_in[3];
    float* out = (float*)d_out;
    tok_kernel<<<kGrid, kThr, 0, stream>>>(x, Wg, bg, Wm, out);
}